// Round 1
// baseline (274.171 us; speedup 1.0000x reference)
//
#include <hip/hip_runtime.h>
#include <cstdint>
#include <cstddef>

// Problem: x[B=512, L=32, H=32, D=128]; per (l,h): Linear(128->128) -> GELU(erf) -> Linear(128->128)
#define LH      1024          // L*H
#define Dd      128           // D == DL == 128
#define BT      128           // batch rows per block
#define XSTRIDE (LH * Dd)     // 131072 elems between consecutive b for fixed (l,h)

typedef __attribute__((ext_vector_type(8))) short bf16x8;   // 8 bf16 (4 VGPRs) per guide §3
typedef __attribute__((ext_vector_type(4))) float f32x4;

static __device__ __forceinline__ short f2bf(float f) {
  uint32_t u = __builtin_bit_cast(uint32_t, f);
  u = (u + 0x7fffu + ((u >> 16) & 1u)) >> 16;   // RNE
  return (short)(u & 0xffffu);
}

static __device__ __forceinline__ float gelu_erf(float v) {
  return 0.5f * v * (1.0f + erff(v * 0.70710678118654752f));
}

__global__ __launch_bounds__(256, 2) void fused_mlp_kernel(
    const float* __restrict__ x, const float* __restrict__ W1,
    const float* __restrict__ b1, const float* __restrict__ W2,
    const float* __restrict__ b2, float* __restrict__ out) {
  // bf16 H tile [b][e], row stride 256 B, XOR-swizzled (byte ^= (row&7)<<4):
  // ds_read_b128 A-frag reads conflict-free (guide G4 / T2 analysis).
  __shared__ alignas(16) short Hs[BT * Dd];

  const int tid  = threadIdx.x;
  const int lane = tid & 63;
  const int wid  = tid >> 6;     // 4 waves, each owns 32 N-columns
  const int lr   = lane & 15;    // MFMA row/col within 16
  const int lg   = lane >> 4;    // k-group (8 elems each)

  const int bid = blockIdx.x;
  const int lh  = bid & (LH - 1);   // consecutive blocks -> different (l,h): bt sweeps reuse W via L3
  const int bt  = bid >> 10;

  const float* w1 = W1 + (size_t)lh * (Dd * Dd);
  const float* w2 = W2 + (size_t)lh * (Dd * Dd);
  const int n0 = wid * 32;

  // per-lane x base: batch row (bt*BT + lr), k-offset lg*8
  const float* xa = x + ((size_t)(bt * BT + lr) * LH + lh) * Dd + lg * 8;

  f32x4 acc[8][2];
#pragma unroll
  for (int mt = 0; mt < 8; ++mt)
#pragma unroll
    for (int nt = 0; nt < 2; ++nt) acc[mt][nt] = (f32x4)0.0f;

  // ---------------- GEMM1: H = gelu(X @ W1 + b1) ----------------
#pragma unroll
  for (int ks = 0; ks < 4; ++ks) {
    const int k0 = ks * 32 + lg * 8;
    bf16x8 af[8];
#pragma unroll
    for (int mt = 0; mt < 8; ++mt) {
      const float4* p = (const float4*)(xa + (size_t)mt * 16 * XSTRIDE + ks * 32);
      float4 u = p[0], v = p[1];
      bf16x8 a;
      a[0] = f2bf(u.x); a[1] = f2bf(u.y); a[2] = f2bf(u.z); a[3] = f2bf(u.w);
      a[4] = f2bf(v.x); a[5] = f2bf(v.y); a[6] = f2bf(v.z); a[7] = f2bf(v.w);
      af[mt] = a;
    }
    bf16x8 bw[2];
#pragma unroll
    for (int nt = 0; nt < 2; ++nt) {
      const float* wp = w1 + (size_t)k0 * Dd + n0 + nt * 16 + lr;
      bf16x8 b;
#pragma unroll
      for (int j = 0; j < 8; ++j) b[j] = f2bf(wp[j * Dd]);
      bw[nt] = b;
    }
#pragma unroll
    for (int mt = 0; mt < 8; ++mt)
#pragma unroll
      for (int nt = 0; nt < 2; ++nt)
        acc[mt][nt] = __builtin_amdgcn_mfma_f32_16x16x32_bf16(af[mt], bw[nt], acc[mt][nt], 0, 0, 0);
  }

  // epilogue 1: bias + exact-erf GELU -> bf16 -> swizzled LDS
  {
    const float bb[2] = {b1[lh * Dd + n0 + lr], b1[lh * Dd + n0 + 16 + lr]};
#pragma unroll
    for (int mt = 0; mt < 8; ++mt)
#pragma unroll
      for (int nt = 0; nt < 2; ++nt) {
        const int e = n0 + nt * 16 + lr;
#pragma unroll
        for (int r = 0; r < 4; ++r) {
          const int b = mt * 16 + lg * 4 + r;        // C/D row = (lane>>4)*4 + reg
          float v = gelu_erf(acc[mt][nt][r] + bb[nt]);
          const int off = (b * 256 + e * 2) ^ ((b & 7) << 4);
          *(short*)((char*)Hs + off) = f2bf(v);
        }
      }
  }
  __syncthreads();

  // ---------------- GEMM2: out = H @ W2 + b2 ----------------
  f32x4 acc2[8][2];
#pragma unroll
  for (int mt = 0; mt < 8; ++mt)
#pragma unroll
    for (int nt = 0; nt < 2; ++nt) acc2[mt][nt] = (f32x4)0.0f;

#pragma unroll
  for (int ks = 0; ks < 4; ++ks) {
    const int k0 = ks * 32 + lg * 8;
    bf16x8 af[8];
#pragma unroll
    for (int mt = 0; mt < 8; ++mt) {
      const int b = mt * 16 + lr;
      const int off = (b * 256 + k0 * 2) ^ ((b & 7) << 4);   // 16B-aligned, conflict-free
      af[mt] = *(const bf16x8*)((const char*)Hs + off);
    }
    bf16x8 bw[2];
#pragma unroll
    for (int nt = 0; nt < 2; ++nt) {
      const float* wp = w2 + (size_t)k0 * Dd + n0 + nt * 16 + lr;
      bf16x8 b;
#pragma unroll
      for (int j = 0; j < 8; ++j) b[j] = f2bf(wp[j * Dd]);
      bw[nt] = b;
    }
#pragma unroll
    for (int mt = 0; mt < 8; ++mt)
#pragma unroll
      for (int nt = 0; nt < 2; ++nt)
        acc2[mt][nt] = __builtin_amdgcn_mfma_f32_16x16x32_bf16(af[mt], bw[nt], acc2[mt][nt], 0, 0, 0);
  }

  // epilogue 2: bias, store f32 (16 consecutive floats per lane-group = 64 B segments)
  {
    const float bb[2] = {b2[lh * Dd + n0 + lr], b2[lh * Dd + n0 + 16 + lr]};
    float* ob = out + ((size_t)(bt * BT) * LH + lh) * Dd;
#pragma unroll
    for (int mt = 0; mt < 8; ++mt)
#pragma unroll
      for (int nt = 0; nt < 2; ++nt) {
        const int e = n0 + nt * 16 + lr;
#pragma unroll
        for (int r = 0; r < 4; ++r) {
          const int b = mt * 16 + lg * 4 + r;
          ob[(size_t)b * XSTRIDE + e] = acc2[mt][nt][r] + bb[nt];
        }
      }
  }
}

extern "C" void kernel_launch(void* const* d_in, const int* in_sizes, int n_in,
                              void* d_out, int out_size, void* d_ws, size_t ws_size,
                              hipStream_t stream) {
  (void)in_sizes; (void)n_in; (void)d_ws; (void)ws_size; (void)out_size;
  const float* x  = (const float*)d_in[0];
  const float* W1 = (const float*)d_in[1];
  const float* b1 = (const float*)d_in[2];
  const float* W2 = (const float*)d_in[3];
  const float* b2 = (const float*)d_in[4];
  float* out = (float*)d_out;
  fused_mlp_kernel<<<dim3(4096), dim3(256), 0, stream>>>(x, W1, b1, W2, b2, out);
}